// Round 1
// baseline (8509.757 us; speedup 1.0000x reference)
//
#include <hip/hip_runtime.h>
#include <hip/hip_bf16.h>
#include <stdint.h>

// BasicLSTM fused persistent-scan kernel for MI355X (gfx950).
// x:[32,512,512]f32  W:[512,4096]f32  U:[1024,4096]f32  b:[4096]f32
// out:[32,512,1024]f32
//
// Strategy: convert inputs to bf16 (W,U transposed to [col][k]); one persistent
// kernel of 128 blocks x 256 threads runs the 512-step scan. Each block owns 8
// hidden units (32 z-columns). Weights live in VGPRs (per-wave K-quarter).
// Cross-block h exchange via agent-scope stores + per-(t,quarter) counters
// (no grid barrier; all 128 blocks trivially co-resident).

typedef __bf16 bf16x8 __attribute__((ext_vector_type(8)));
typedef float f32x16 __attribute__((ext_vector_type(16)));

#define B_   32
#define T_   512
#define KIN  512
#define H_   1024
#define NBLK 128

// workspace layout (bytes)
#define OFF_X   0ull                   // bf16 [32][512][512]   x
#define OFF_WT  16777216ull            // bf16 [4096][512]      W^T
#define OFF_UT  20971520ull            // bf16 [4096][1024]     U^T
#define OFF_H   29360128ull            // bf16 [513][32][1024]  h history
#define OFF_CNT 62980096ull            // u32  [513][4]         ready counters
#define WS_NEED (OFF_CNT + 513ull*4*4)

__device__ __forceinline__ unsigned short f2bf(float f) {
    uint32_t u = __float_as_uint(f);
    uint32_t r = (u + 0x7FFFu + ((u >> 16) & 1u)) >> 16;   // RNE
    return (unsigned short)r;
}

__device__ __forceinline__ float sigm(float x) { return 1.f / (1.f + __expf(-x)); }
__device__ __forceinline__ float tanh_(float x) {
    float e = __expf(fminf(2.f * x, 60.f));                // x<<0 -> e->0 -> -1
    return (e - 1.f) / (e + 1.f);
}

// ---------- prep: f32 -> bf16 copy (vectorized) ----------
__global__ void k_cvt_x(const float* __restrict__ x, unsigned short* __restrict__ xb, int n4) {
    int i = blockIdx.x * blockDim.x + threadIdx.x;
    if (i < n4) {
        float4 v = ((const float4*)x)[i];
        ushort4 o;
        o.x = f2bf(v.x); o.y = f2bf(v.y); o.z = f2bf(v.z); o.w = f2bf(v.w);
        ((ushort4*)xb)[i] = o;
    }
}

// ---------- prep: f32 [R][C] -> bf16 [C][R] transpose ----------
__global__ void k_tc(const float* __restrict__ in, unsigned short* __restrict__ out, int R, int C) {
    __shared__ float t[32][33];
    int c0 = blockIdx.x * 32, r0 = blockIdx.y * 32;
    int tx = threadIdx.x, ty = threadIdx.y;   // block (32,8)
#pragma unroll
    for (int k = 0; k < 4; ++k)
        t[ty + 8 * k][tx] = in[(size_t)(r0 + ty + 8 * k) * C + c0 + tx];
    __syncthreads();
#pragma unroll
    for (int k = 0; k < 4; ++k)
        out[(size_t)(c0 + ty + 8 * k) * R + r0 + tx] = f2bf(t[tx][ty + 8 * k]);
}

// ---------- main fused LSTM scan ----------
__launch_bounds__(256, 1)
__global__ void k_lstm(const unsigned short* __restrict__ xb,
                       const unsigned short* __restrict__ Wt,
                       const unsigned short* __restrict__ Ut,
                       const float* __restrict__ b,
                       unsigned short* hall,
                       uint32_t* cnt,
                       float* __restrict__ out) {
    __shared__ float          zl[4 * 32 * 33];          // per-wave partial z^T tiles
    __shared__ __align__(16) float hout[256];           // h f32 [row][unit]
    __shared__ __align__(4)  unsigned short hpk[256];   // h bf16 [row][unit]

    const int tid = threadIdx.x, bid = blockIdx.x;
    const int l = tid & 63, w = tid >> 6;               // lane, wave(=K quarter)
    const int cc = l & 31;                              // col-in-block / A row
    const int kg = l >> 5;                              // k subgroup (0/1)
    const int ucol = (cc >> 3) * 1024 + bid * 8 + (cc & 7);  // column in 4H
    const int gr = tid & 31, gu = tid >> 5;             // gates: batch row, unit

    // resident weight fragments (VGPRs): wave w covers h-k in [256w,256w+256),
    // x-k in [128w,128w+128)
    bf16x8 uf[16], wf[8], xf[8];
    {
        const unsigned short* p = Ut + (size_t)ucol * 1024 + 256 * w + kg * 8;
#pragma unroll
        for (int ks = 0; ks < 16; ++ks) uf[ks] = *(const bf16x8*)(p + ks * 16);
    }
    {
        const unsigned short* p = Wt + (size_t)ucol * 512 + 128 * w + kg * 8;
#pragma unroll
        for (int ks = 0; ks < 8; ++ks) wf[ks] = *(const bf16x8*)(p + ks * 16);
    }
    float bv[4];
#pragma unroll
    for (int g = 0; g < 4; ++g) bv[g] = b[g * 1024 + bid * 8 + gu];

    const unsigned short* xrowp = xb + (size_t)(l & 31) * (T_ * KIN) + 128 * w + kg * 8;
    const unsigned short* hrowp = hall + (size_t)(l & 31) * 1024 + 256 * w + kg * 8;

    // preload x fragments for t=0
#pragma unroll
    for (int ks = 0; ks < 8; ++ks) xf[ks] = *(const bf16x8*)(xrowp + ks * 16);

    float c = 0.f;

    for (int t = 0; t < T_; ++t) {
        f32x16 acc;
#pragma unroll
        for (int i = 0; i < 16; ++i) acc[i] = 0.f;

        bf16x8 hf[16];
        if (t > 0) {
            // wait for the 32 producers of this wave's K quarter
            uint32_t* cp = cnt + t * 4 + w;
            while (__hip_atomic_load(cp, __ATOMIC_RELAXED, __HIP_MEMORY_SCOPE_AGENT) < 32u)
                __builtin_amdgcn_s_sleep(1);
            __builtin_amdgcn_fence(__ATOMIC_ACQUIRE, "agent");
            const unsigned short* hp = hrowp + (size_t)t * (B_ * H_);
#pragma unroll
            for (int ks = 0; ks < 16; ++ks) hf[ks] = *(const bf16x8*)(hp + ks * 16);
        }

        // x part (fragments already resident) — overlaps h loads
#pragma unroll
        for (int ks = 0; ks < 8; ++ks)
            acc = __builtin_amdgcn_mfma_f32_32x32x16_bf16(xf[ks], wf[ks], acc, 0, 0, 0);

        // prefetch next step's x fragments
        if (t < T_ - 1) {
            const unsigned short* xp = xrowp + (size_t)(t + 1) * KIN;
#pragma unroll
            for (int ks = 0; ks < 8; ++ks) xf[ks] = *(const bf16x8*)(xp + ks * 16);
        }

        if (t > 0) {
#pragma unroll
            for (int ks = 0; ks < 16; ++ks)
                acc = __builtin_amdgcn_mfma_f32_32x32x16_bf16(hf[ks], uf[ks], acc, 0, 0, 0);
        }

        // write partial z^T tile: zl[w][col][row]
#pragma unroll
        for (int i = 0; i < 16; ++i) {
            int zr = (i & 3) + 8 * (i >> 2) + 4 * kg;   // C/D row mapping (m74/m101)
            zl[(w * 32 + cc) * 33 + zr] = acc[i];
        }
        __syncthreads();

        // gates: thread = (batch row gr, unit gu); sum 4 wave partials
        float zg[4];
#pragma unroll
        for (int g = 0; g < 4; ++g) {
            float s = bv[g];
#pragma unroll
            for (int ww = 0; ww < 4; ++ww)
                s += zl[(ww * 32 + g * 8 + gu) * 33 + gr];
            zg[g] = s;
        }
        float i_ = sigm(zg[0]);
        float f_ = sigm(zg[1]);
        float g_ = tanh_(zg[2]);
        float o_ = sigm(zg[3]);
        c = f_ * c + i_ * g_;
        float h = o_ * tanh_(c);
        hout[gr * 8 + gu] = h;
        hpk[gr * 8 + gu] = f2bf(h);
        __syncthreads();

        // write output (coalesced 16B) and publish h (agent-scope u32 stores)
        if (tid < 64) {
            int r = tid >> 1, q4 = (tid & 1) * 4;
            float4 v = *(const float4*)&hout[r * 8 + q4];
            *(float4*)(out + (size_t)r * (T_ * H_) + (size_t)t * H_ + bid * 8 + q4) = v;
        }
        if (tid < 128) {
            int r = tid >> 2, p = tid & 3;
            uint32_t v = ((const uint32_t*)hpk)[r * 4 + p];
            uint32_t* dst = (uint32_t*)(hall + (size_t)(t + 1) * (B_ * H_) + r * 1024 + bid * 8 + p * 2);
            __hip_atomic_store(dst, v, __ATOMIC_RELAXED, __HIP_MEMORY_SCOPE_AGENT);
        }
        __syncthreads();   // drains all publish stores (vmcnt) before signaling

        if (tid == 0)
            __hip_atomic_fetch_add(cnt + (t + 1) * 4 + (bid >> 5), 1u,
                                   __ATOMIC_RELEASE, __HIP_MEMORY_SCOPE_AGENT);
    }
}

extern "C" void kernel_launch(void* const* d_in, const int* in_sizes, int n_in,
                              void* d_out, int out_size, void* d_ws, size_t ws_size,
                              hipStream_t stream) {
    const float* x = (const float*)d_in[0];
    const float* W = (const float*)d_in[1];
    const float* U = (const float*)d_in[2];
    const float* b = (const float*)d_in[3];
    float* out = (float*)d_out;
    char* ws = (char*)d_ws;

    unsigned short* xb   = (unsigned short*)(ws + OFF_X);
    unsigned short* Wt   = (unsigned short*)(ws + OFF_WT);
    unsigned short* Ut   = (unsigned short*)(ws + OFF_UT);
    unsigned short* hall = (unsigned short*)(ws + OFF_H);
    uint32_t*       cnt  = (uint32_t*)(ws + OFF_CNT);

    (void)in_sizes; (void)n_in; (void)out_size; (void)ws_size;

    hipMemsetAsync(cnt, 0, 513 * 4 * 4, stream);

    int n4 = (B_ * T_ * KIN) / 4;
    k_cvt_x<<<(n4 + 255) / 256, 256, 0, stream>>>(x, xb, n4);

    dim3 tb(32, 8);
    k_tc<<<dim3(4096 / 32, KIN / 32), tb, 0, stream>>>(W, Wt, KIN, 4096);
    k_tc<<<dim3(4096 / 32, H_ / 32), tb, 0, stream>>>(U, Ut, H_, 4096);

    k_lstm<<<NBLK, 256, 0, stream>>>(xb, Wt, Ut, b, hall, cnt, out);
}

// Round 2
// 2654.589 us; speedup vs baseline: 3.2057x; 3.2057x over previous
//
#include <hip/hip_runtime.h>
#include <hip/hip_bf16.h>
#include <stdint.h>

// BasicLSTM fused persistent-scan kernel for MI355X (gfx950).
// x:[32,512,512]f32  W:[512,4096]f32  U:[1024,4096]f32  b:[4096]f32
// out:[32,512,1024]f32
//
// Round 2: fence-free producer/consumer scan.
//  - h published via relaxed agent-scope (write-through sc0/sc1) stores
//  - ordering via s_waitcnt vmcnt(0) + per-block relaxed flag store
//  - consumers poll 32 flags with one coalesced bypassing load per wave
//  - NO per-step buffer_wbl2 / buffer_inv (the round-1 killer: 16.6us/step)
//  - one agent acquire fence at kernel entry (clears stale poison lines)

typedef __bf16 bf16x8 __attribute__((ext_vector_type(8)));
typedef float f32x16 __attribute__((ext_vector_type(16)));

#define B_   32
#define T_   512
#define KIN  512
#define H_   1024
#define NBLK 128

// workspace layout (bytes)
#define OFF_X    0ull                  // bf16 [32][512][512]   x
#define OFF_WT   16777216ull           // bf16 [4096][512]      W^T
#define OFF_UT   20971520ull           // bf16 [4096][1024]     U^T
#define OFF_H    29360128ull           // bf16 [512][32][1024]  h history (slot t = h input of step t)
#define OFF_FLAG 62914560ull           // u32  [512][128]       per-(t,block) ready flags
#define WS_NEED  (OFF_FLAG + 512ull*128*4)

__device__ __forceinline__ unsigned short f2bf(float f) {
    uint32_t u = __float_as_uint(f);
    uint32_t r = (u + 0x7FFFu + ((u >> 16) & 1u)) >> 16;   // RNE
    return (unsigned short)r;
}

__device__ __forceinline__ float sigm(float x) { return 1.f / (1.f + __expf(-x)); }
__device__ __forceinline__ float tanh_(float x) {
    float e = __expf(fminf(2.f * x, 60.f));                // x<<0 -> e->0 -> -1
    return (e - 1.f) / (e + 1.f);
}

// ---------- prep: f32 -> bf16 copy (vectorized) ----------
__global__ void k_cvt_x(const float* __restrict__ x, unsigned short* __restrict__ xb, int n4) {
    int i = blockIdx.x * blockDim.x + threadIdx.x;
    if (i < n4) {
        float4 v = ((const float4*)x)[i];
        ushort4 o;
        o.x = f2bf(v.x); o.y = f2bf(v.y); o.z = f2bf(v.z); o.w = f2bf(v.w);
        ((ushort4*)xb)[i] = o;
    }
}

// ---------- prep: f32 [R][C] -> bf16 [C][R] transpose ----------
__global__ void k_tc(const float* __restrict__ in, unsigned short* __restrict__ out, int R, int C) {
    __shared__ float t[32][33];
    int c0 = blockIdx.x * 32, r0 = blockIdx.y * 32;
    int tx = threadIdx.x, ty = threadIdx.y;   // block (32,8)
#pragma unroll
    for (int k = 0; k < 4; ++k)
        t[ty + 8 * k][tx] = in[(size_t)(r0 + ty + 8 * k) * C + c0 + tx];
    __syncthreads();
#pragma unroll
    for (int k = 0; k < 4; ++k)
        out[(size_t)(c0 + ty + 8 * k) * R + r0 + tx] = f2bf(t[tx][ty + 8 * k]);
}

// ---------- main fused LSTM scan ----------
__launch_bounds__(256, 1)
__global__ void k_lstm(const unsigned short* __restrict__ xb,
                       const unsigned short* __restrict__ Wt,
                       const unsigned short* __restrict__ Ut,
                       const float* __restrict__ b,
                       unsigned short* hall,
                       uint32_t* flags,
                       float* __restrict__ out) {
    __shared__ float          zl[4 * 32 * 33];          // per-wave partial z^T tiles
    __shared__ __align__(16) float hout[256];           // h f32 [row][unit]
    __shared__ __align__(16) unsigned short hpk[256];   // h bf16 [row][unit]

    const int tid = threadIdx.x, bid = blockIdx.x;
    const int l = tid & 63, w = tid >> 6;               // lane, wave(=K quarter)
    const int cc = l & 31;                              // col-in-block / A row
    const int kg = l >> 5;                              // k subgroup (0/1)
    const int ucol = (cc >> 3) * 1024 + bid * 8 + (cc & 7);  // column in 4H
    const int gr = tid & 31, gu = tid >> 5;             // gates: batch row, unit

    // one-time acquire: drop any stale (poison) lines from this XCD's L1/L2
    __builtin_amdgcn_fence(__ATOMIC_ACQUIRE, "agent");

    // resident weight fragments (VGPRs): wave w covers h-k in [256w,256w+256),
    // x-k in [128w,128w+128)
    bf16x8 uf[16], wf[8], xf[8];
    {
        const unsigned short* p = Ut + (size_t)ucol * 1024 + 256 * w + kg * 8;
#pragma unroll
        for (int ks = 0; ks < 16; ++ks) uf[ks] = *(const bf16x8*)(p + ks * 16);
    }
    {
        const unsigned short* p = Wt + (size_t)ucol * 512 + 128 * w + kg * 8;
#pragma unroll
        for (int ks = 0; ks < 8; ++ks) wf[ks] = *(const bf16x8*)(p + ks * 16);
    }
    float bv[4];
#pragma unroll
    for (int g = 0; g < 4; ++g) bv[g] = b[g * 1024 + bid * 8 + gu];

    const unsigned short* xrowp = xb + (size_t)(l & 31) * (T_ * KIN) + 128 * w + kg * 8;
    const unsigned short* hrowp = hall + (size_t)(l & 31) * 1024 + 256 * w + kg * 8;

    // preload x fragments for t=0
#pragma unroll
    for (int ks = 0; ks < 8; ++ks) xf[ks] = *(const bf16x8*)(xrowp + ks * 16);

    float c = 0.f;

    for (int t = 0; t < T_; ++t) {
        f32x16 acc;
#pragma unroll
        for (int i = 0; i < 16; ++i) acc[i] = 0.f;

        // x part first (fragments already resident) — overlaps the flag wait
#pragma unroll
        for (int ks = 0; ks < 8; ++ks)
            acc = __builtin_amdgcn_mfma_f32_32x32x16_bf16(xf[ks], wf[ks], acc, 0, 0, 0);

        // prefetch next step's x fragments (in flight during the poll)
        if (t < T_ - 1) {
            const unsigned short* xp = xrowp + (size_t)(t + 1) * KIN;
#pragma unroll
            for (int ks = 0; ks < 8; ++ks) xf[ks] = *(const bf16x8*)(xp + ks * 16);
        }

        if (t > 0) {
            // wait for the 32 producer blocks of this wave's K quarter:
            // lane i polls block (32w+i)'s flag — one coalesced bypassing load
            const uint32_t* fp = flags + (size_t)t * NBLK + w * 32 + (l & 31);
            uint32_t f = __hip_atomic_load(fp, __ATOMIC_RELAXED, __HIP_MEMORY_SCOPE_AGENT);
            while (__any(f == 0)) {
                __builtin_amdgcn_s_sleep(1);
                f = __hip_atomic_load(fp, __ATOMIC_RELAXED, __HIP_MEMORY_SCOPE_AGENT);
            }
            asm volatile("" ::: "memory");   // no hoisting of h loads above the poll

            const unsigned short* hp = hrowp + (size_t)t * (B_ * H_);
            bf16x8 hf[16];
#pragma unroll
            for (int ks = 0; ks < 16; ++ks) hf[ks] = *(const bf16x8*)(hp + ks * 16);
#pragma unroll
            for (int ks = 0; ks < 16; ++ks)
                acc = __builtin_amdgcn_mfma_f32_32x32x16_bf16(hf[ks], uf[ks], acc, 0, 0, 0);
        }

        // write partial z^T tile: zl[w][col][row]
#pragma unroll
        for (int i = 0; i < 16; ++i) {
            int zr = (i & 3) + 8 * (i >> 2) + 4 * kg;   // C/D row mapping (m74/m101)
            zl[(w * 32 + cc) * 33 + zr] = acc[i];
        }
        __syncthreads();

        // gates: thread = (batch row gr, unit gu); sum 4 wave partials
        float zg[4];
#pragma unroll
        for (int g = 0; g < 4; ++g) {
            float s = bv[g];
#pragma unroll
            for (int ww = 0; ww < 4; ++ww)
                s += zl[(ww * 32 + g * 8 + gu) * 33 + gr];
            zg[g] = s;
        }
        float i_ = sigm(zg[0]);
        float f_ = sigm(zg[1]);
        float g_ = tanh_(zg[2]);
        float o_ = sigm(zg[3]);
        c = f_ * c + i_ * g_;
        float h = o_ * tanh_(c);
        hout[gr * 8 + gu] = h;
        hpk[gr * 8 + gu] = f2bf(h);
        __syncthreads();

        // wave 0: write output, publish h (write-through), raise flag.
        // No third barrier — other waves run ahead to the next poll.
        if (w == 0) {
            int r = l >> 1, half = l & 1;
            float4 v = *(const float4*)&hout[r * 8 + half * 4];
            *(float4*)(out + (size_t)r * (T_ * H_) + (size_t)t * H_ + bid * 8 + half * 4) = v;
            if (t < T_ - 1) {
                uint64_t pv = ((const uint64_t*)hpk)[r * 2 + half];
                uint64_t* dst = (uint64_t*)(hall + (size_t)(t + 1) * (B_ * H_) + r * 1024 + bid * 8 + half * 4);
                __hip_atomic_store(dst, pv, __ATOMIC_RELAXED, __HIP_MEMORY_SCOPE_AGENT);
                __builtin_amdgcn_s_waitcnt(0);   // h stores complete at coherence point
                if (l == 0)
                    __hip_atomic_store(flags + (size_t)(t + 1) * NBLK + bid, 1u,
                                       __ATOMIC_RELAXED, __HIP_MEMORY_SCOPE_AGENT);
            }
        }
    }
}

extern "C" void kernel_launch(void* const* d_in, const int* in_sizes, int n_in,
                              void* d_out, int out_size, void* d_ws, size_t ws_size,
                              hipStream_t stream) {
    const float* x = (const float*)d_in[0];
    const float* W = (const float*)d_in[1];
    const float* U = (const float*)d_in[2];
    const float* b = (const float*)d_in[3];
    float* out = (float*)d_out;
    char* ws = (char*)d_ws;

    unsigned short* xb   = (unsigned short*)(ws + OFF_X);
    unsigned short* Wt   = (unsigned short*)(ws + OFF_WT);
    unsigned short* Ut   = (unsigned short*)(ws + OFF_UT);
    unsigned short* hall = (unsigned short*)(ws + OFF_H);
    uint32_t*       flags = (uint32_t*)(ws + OFF_FLAG);

    (void)in_sizes; (void)n_in; (void)out_size; (void)ws_size;

    hipMemsetAsync(flags, 0, 512 * 128 * 4, stream);

    int n4 = (B_ * T_ * KIN) / 4;
    k_cvt_x<<<(n4 + 255) / 256, 256, 0, stream>>>(x, xb, n4);

    dim3 tb(32, 8);
    k_tc<<<dim3(4096 / 32, KIN / 32), tb, 0, stream>>>(W, Wt, KIN, 4096);
    k_tc<<<dim3(4096 / 32, H_ / 32), tb, 0, stream>>>(U, Ut, H_, 4096);

    k_lstm<<<NBLK, 256, 0, stream>>>(xb, Wt, Ut, b, hall, flags, out);
}

// Round 3
// 1393.224 us; speedup vs baseline: 6.1080x; 1.9054x over previous
//
#include <hip/hip_runtime.h>
#include <hip/hip_bf16.h>
#include <stdint.h>

// BasicLSTM fused persistent-scan kernel for MI355X (gfx950).
// x:[32,512,512]f32  W:[512,4096]f32  U:[1024,4096]f32  b:[4096]f32
// out:[32,512,1024]f32
//
// Round 3: poll-the-data handshake.
//  - h history prefilled with 0xFF sentinel (bf16 NaN; h can never be NaN)
//  - producers fire-and-forget sc1 stores (no vmcnt drain, no flag)
//  - consumers poll their h fragments with bypassing sc0 sc1 dwordx4 loads;
//    on success data is already in registers (one L3 RTT on critical path)
//  - h layout [t][ublock][row][8units]: publish = 512 contiguous B per block
//  - weights pinned in regs via asm "+v" (round-2 compiler reloaded them)
//  - two accumulators: post-poll MFMA chain 8 deep instead of 24

typedef __bf16 bf16x8 __attribute__((ext_vector_type(8)));
typedef float f32x16 __attribute__((ext_vector_type(16)));
typedef int   i32x4  __attribute__((ext_vector_type(4)));

#define B_   32
#define T_   512
#define KIN  512
#define H_   1024
#define NBLK 128

// workspace layout (bytes)
#define OFF_X    0ull                  // bf16 [32][512][512]   x
#define OFF_WT   16777216ull           // bf16 [4096][512]      W^T
#define OFF_UT   20971520ull           // bf16 [4096][1024]     U^T
#define OFF_H    29360128ull           // bf16 [512][128][32][8] h history (slot t read at step t)
#define SLOT_B   65536ull              // 128*32*8*2
#define WS_NEED  (OFF_H + 512ull*SLOT_B)

__device__ __forceinline__ unsigned short f2bf(float f) {
    uint32_t u = __float_as_uint(f);
    uint32_t r = (u + 0x7FFFu + ((u >> 16) & 1u)) >> 16;   // RNE
    return (unsigned short)r;
}

__device__ __forceinline__ float sigm(float x) { return 1.f / (1.f + __expf(-x)); }
__device__ __forceinline__ float tanh_(float x) {
    float e = __expf(fminf(2.f * x, 60.f));                // x<<0 -> e->0 -> -1
    return (e - 1.f) / (e + 1.f);
}

// ---------- prep: f32 -> bf16 copy (vectorized) ----------
__global__ void k_cvt_x(const float* __restrict__ x, unsigned short* __restrict__ xb, int n4) {
    int i = blockIdx.x * blockDim.x + threadIdx.x;
    if (i < n4) {
        float4 v = ((const float4*)x)[i];
        ushort4 o;
        o.x = f2bf(v.x); o.y = f2bf(v.y); o.z = f2bf(v.z); o.w = f2bf(v.w);
        ((ushort4*)xb)[i] = o;
    }
}

// ---------- prep: f32 [R][C] -> bf16 [C][R] transpose ----------
__global__ void k_tc(const float* __restrict__ in, unsigned short* __restrict__ out, int R, int C) {
    __shared__ float t[32][33];
    int c0 = blockIdx.x * 32, r0 = blockIdx.y * 32;
    int tx = threadIdx.x, ty = threadIdx.y;   // block (32,8)
#pragma unroll
    for (int k = 0; k < 4; ++k)
        t[ty + 8 * k][tx] = in[(size_t)(r0 + ty + 8 * k) * C + c0 + tx];
    __syncthreads();
#pragma unroll
    for (int k = 0; k < 4; ++k)
        out[(size_t)(c0 + ty + 8 * k) * R + r0 + tx] = f2bf(t[tx][ty + 8 * k]);
}

#define KEEPV(x) asm volatile("" : "+v"(x))

// bypassing (coherent, L1+L2-miss) 16B load with immediate offset
#define POLL_LD(dst, base, imm)                                              \
    asm volatile("global_load_dwordx4 %0, %1, off offset:" #imm " sc0 sc1"  \
                 : "=v"(dst) : "v"(base))

// ---------- main fused LSTM scan ----------
__launch_bounds__(256, 1)
__global__ void k_lstm(const unsigned short* __restrict__ xb,
                       const unsigned short* __restrict__ Wt,
                       const unsigned short* __restrict__ Ut,
                       const float* __restrict__ b,
                       unsigned short* hall,
                       float* __restrict__ out) {
    __shared__ float          zl[4 * 32 * 33];          // per-wave partial z^T tiles
    __shared__ __align__(16) float hout[256];           // h f32 [row][unit]
    __shared__ __align__(16) unsigned short hpk[256];   // h bf16 [row][unit]

    const int tid = threadIdx.x, bid = blockIdx.x;
    const int l = tid & 63, w = tid >> 6;               // lane, wave(=K quarter)
    const int cc = l & 31;                              // batch row / A row
    const int kg = l >> 5;                              // k subgroup (0/1)
    const int ucol = (cc >> 3) * 1024 + bid * 8 + (cc & 7);  // column in 4H
    const int gr = tid & 31, gu = tid >> 5;             // gates: batch row, unit

    __builtin_amdgcn_fence(__ATOMIC_ACQUIRE, "agent");

    // resident weight fragments: wave w covers h-k [256w,256w+256), x-k [128w,128w+128)
    bf16x8 uf[16], wf[8], xf[8];
    {
        const unsigned short* p = Ut + (size_t)ucol * 1024 + 256 * w + kg * 8;
#pragma unroll
        for (int ks = 0; ks < 16; ++ks) uf[ks] = *(const bf16x8*)(p + ks * 16);
    }
    {
        const unsigned short* p = Wt + (size_t)ucol * 512 + 128 * w + kg * 8;
#pragma unroll
        for (int ks = 0; ks < 8; ++ks) wf[ks] = *(const bf16x8*)(p + ks * 16);
    }
    float bv[4];
#pragma unroll
    for (int g = 0; g < 4; ++g) bv[g] = b[g * 1024 + bid * 8 + gu];

    const unsigned short* xrowp = xb + (size_t)cc * (T_ * KIN) + 128 * w + kg * 8;
    // consumer poll base: slot + ublock(32w+kg)*512 + row*16 ; frag ks at +ks*1024
    const char* hbase = (const char*)hall + (size_t)w * 16384 + (size_t)kg * 512 + (size_t)cc * 16;

#pragma unroll
    for (int ks = 0; ks < 8; ++ks) xf[ks] = *(const bf16x8*)(xrowp + ks * 16);

    float c = 0.f;

    for (int t = 0; t < T_; ++t) {
        // pin loop-invariant register state (stop rematerialization/reload)
#pragma unroll
        for (int ks = 0; ks < 16; ++ks) KEEPV(uf[ks]);
#pragma unroll
        for (int ks = 0; ks < 8; ++ks) KEEPV(wf[ks]);

        f32x16 accA, accB;
#pragma unroll
        for (int i = 0; i < 16; ++i) { accA[i] = 0.f; accB[i] = 0.f; }

        // x part first (registers already resident) — off the handshake path
#pragma unroll
        for (int ks = 0; ks < 8; ++ks)
            accA = __builtin_amdgcn_mfma_f32_32x32x16_bf16(xf[ks], wf[ks], accA, 0, 0, 0);

        // prefetch next step's x fragments
        if (t < T_ - 1) {
            const unsigned short* xp = xrowp + (size_t)(t + 1) * KIN;
#pragma unroll
            for (int ks = 0; ks < 8; ++ks) xf[ks] = *(const bf16x8*)(xp + ks * 16);
        }

        if (t > 0) {
            // poll-the-data: bypassing loads of this wave's 16 h fragments,
            // retry until no dword equals the 0xFFFFFFFF sentinel
            const char* hb0 = hbase + (size_t)t * SLOT_B;
            const char* hb4 = hb0 + 4096;
            const char* hb8 = hb0 + 8192;
            const char* hbC = hb0 + 12288;
            i32x4 hd[16];
            bool bad;
            do {
                POLL_LD(hd[0],  hb0, 0);    POLL_LD(hd[1],  hb0, 1024);
                POLL_LD(hd[2],  hb0, 2048); POLL_LD(hd[3],  hb0, 3072);
                POLL_LD(hd[4],  hb4, 0);    POLL_LD(hd[5],  hb4, 1024);
                POLL_LD(hd[6],  hb4, 2048); POLL_LD(hd[7],  hb4, 3072);
                POLL_LD(hd[8],  hb8, 0);    POLL_LD(hd[9],  hb8, 1024);
                POLL_LD(hd[10], hb8, 2048); POLL_LD(hd[11], hb8, 3072);
                POLL_LD(hd[12], hbC, 0);    POLL_LD(hd[13], hbC, 1024);
                POLL_LD(hd[14], hbC, 2048); POLL_LD(hd[15], hbC, 3072);
                asm volatile("s_waitcnt vmcnt(0)" ::: "memory");
                __builtin_amdgcn_sched_barrier(0);
                uint32_t mx = 0u;
#pragma unroll
                for (int ks = 0; ks < 16; ++ks) {
                    uint32_t a0 = (uint32_t)hd[ks].x, a1 = (uint32_t)hd[ks].y;
                    uint32_t a2 = (uint32_t)hd[ks].z, a3 = (uint32_t)hd[ks].w;
                    uint32_t m01 = a0 > a1 ? a0 : a1;
                    uint32_t m23 = a2 > a3 ? a2 : a3;
                    uint32_t m = m01 > m23 ? m01 : m23;
                    mx = mx > m ? mx : m;
                }
                bad = __any(mx == 0xFFFFFFFFu);
                if (bad) __builtin_amdgcn_s_sleep(2);
            } while (bad);

            // h MFMAs: two independent 8-deep chains
#pragma unroll
            for (int ks = 0; ks < 8; ++ks) {
                bf16x8 hf = *(bf16x8*)&hd[ks];
                accB = __builtin_amdgcn_mfma_f32_32x32x16_bf16(hf, uf[ks], accB, 0, 0, 0);
            }
#pragma unroll
            for (int ks = 8; ks < 16; ++ks) {
                bf16x8 hf = *(bf16x8*)&hd[ks];
                accA = __builtin_amdgcn_mfma_f32_32x32x16_bf16(hf, uf[ks], accA, 0, 0, 0);
            }
        }

        // write partial z^T tile: zl[w][col][row]
#pragma unroll
        for (int i = 0; i < 16; ++i) {
            int zr = (i & 3) + 8 * (i >> 2) + 4 * kg;   // C/D row mapping (m74/m101)
            zl[(w * 32 + cc) * 33 + zr] = accA[i] + accB[i];
        }
        __syncthreads();

        // gates: thread = (batch row gr, unit gu); sum 4 wave partials
        float zg[4];
#pragma unroll
        for (int g = 0; g < 4; ++g) {
            float s = bv[g];
#pragma unroll
            for (int ww = 0; ww < 4; ++ww)
                s += zl[(ww * 32 + g * 8 + gu) * 33 + gr];
            zg[g] = s;
        }
        float i_ = sigm(zg[0]);
        float f_ = sigm(zg[1]);
        float g_ = tanh_(zg[2]);
        float o_ = sigm(zg[3]);
        c = f_ * c + i_ * g_;
        float h = o_ * tanh_(c);
        hout[gr * 8 + gu] = h;
        hpk[gr * 8 + gu] = f2bf(h);
        __syncthreads();

        // wave 0: out store + fire-and-forget publish. No drain, no flag.
        if (w == 0) {
            int r = l >> 1, half = l & 1;
            float4 v = *(const float4*)&hout[r * 8 + half * 4];
            *(float4*)(out + (size_t)r * (T_ * H_) + (size_t)t * H_ + bid * 8 + half * 4) = v;
            if (t < T_ - 1) {
                uint64_t pv = ((const uint64_t*)hpk)[l];
                uint64_t* dst = (uint64_t*)(hall + ((size_t)(t + 1) * SLOT_B + (size_t)bid * 512) / 2) + l;
                __hip_atomic_store(dst, pv, __ATOMIC_RELAXED, __HIP_MEMORY_SCOPE_AGENT);
            }
        }
    }
}

extern "C" void kernel_launch(void* const* d_in, const int* in_sizes, int n_in,
                              void* d_out, int out_size, void* d_ws, size_t ws_size,
                              hipStream_t stream) {
    const float* x = (const float*)d_in[0];
    const float* W = (const float*)d_in[1];
    const float* U = (const float*)d_in[2];
    const float* b = (const float*)d_in[3];
    float* out = (float*)d_out;
    char* ws = (char*)d_ws;

    unsigned short* xb   = (unsigned short*)(ws + OFF_X);
    unsigned short* Wt   = (unsigned short*)(ws + OFF_WT);
    unsigned short* Ut   = (unsigned short*)(ws + OFF_UT);
    unsigned short* hall = (unsigned short*)(ws + OFF_H);

    (void)in_sizes; (void)n_in; (void)out_size; (void)ws_size;

    // sentinel-fill h history slots 1..511 (slot 0 never read)
    hipMemsetAsync(ws + OFF_H + SLOT_B, 0xFF, 511ull * SLOT_B, stream);

    int n4 = (B_ * T_ * KIN) / 4;
    k_cvt_x<<<(n4 + 255) / 256, 256, 0, stream>>>(x, xb, n4);

    dim3 tb(32, 8);
    k_tc<<<dim3(4096 / 32, KIN / 32), tb, 0, stream>>>(W, Wt, KIN, 4096);
    k_tc<<<dim3(4096 / 32, H_ / 32), tb, 0, stream>>>(U, Ut, H_, 4096);

    k_lstm<<<NBLK, 256, 0, stream>>>(xb, Wt, Ut, b, hall, out);
}